// Round 6
// baseline (286.815 us; speedup 1.0000x reference)
//
#include <hip/hip_runtime.h>
#include <math.h>

#define NN 50000
#define NE 800000
#define NG 50
#define F0 128
#define F1 64
#define F2 32
#define NPB 256                  // nodes per bucket (bucket = dst >> 8)
#define NBK 196                  // ceil(NN/NPB)
#define CHUNK 4096
#define NC 196                   // ceil(NE/CHUNK)

__device__ __forceinline__ float lrelu(float v, float slope) {
    return v > 0.0f ? v : v * slope;
}

// ---- GEMM1: z = x@W (NN x 128 @ 128 x 64), register-blocked.
// Block tile: 32 rows x 64 cols. Thread (j = tid&63, rg = tid>>6) computes
// 8 rows for col j. Wave == rowgroup -> xs reads are wave-uniform broadcast.
// el/er fused via wave shfl reduction.
__global__ __launch_bounds__(256) void gemm1_kernel(
    const float* __restrict__ x, const float* __restrict__ W,
    const float* __restrict__ al, const float* __restrict__ ar,
    float* __restrict__ z, float* __restrict__ el, float* __restrict__ er)
{
    __shared__ float Ws[F0 * F1];     // 32 KB
    __shared__ float xs[32][F0];      // 16 KB
    int tid = threadIdx.x;
    int r0 = blockIdx.x * 32;

    // stage W: 2048 float4, 8 per thread
    {
        const float4* W4 = reinterpret_cast<const float4*>(W);
        float4* Ws4 = reinterpret_cast<float4*>(Ws);
        #pragma unroll
        for (int i = 0; i < 8; ++i) Ws4[tid + i * 256] = W4[tid + i * 256];
    }
    // stage x tile: 1024 float4 slots (row = s>>5, col4 = s&31), 4 per thread
    {
        float4 zero = {0.f, 0.f, 0.f, 0.f};
        #pragma unroll
        for (int i = 0; i < 4; ++i) {
            int s = tid + i * 256;
            int row = s >> 5, c4 = s & 31;
            int grow = r0 + row;
            float4 v = (grow < NN)
                ? reinterpret_cast<const float4*>(x)[(size_t)grow * 32 + c4] : zero;
            *reinterpret_cast<float4*>(&xs[row][c4 * 4]) = v;
        }
    }
    __syncthreads();

    int j = tid & 63, rg = tid >> 6;
    float acc[8] = {0.f, 0.f, 0.f, 0.f, 0.f, 0.f, 0.f, 0.f};
    for (int k4 = 0; k4 < F0 / 4; ++k4) {
        float w0 = Ws[(k4 * 4 + 0) * F1 + j];
        float w1 = Ws[(k4 * 4 + 1) * F1 + j];
        float w2 = Ws[(k4 * 4 + 2) * F1 + j];
        float w3 = Ws[(k4 * 4 + 3) * F1 + j];
        #pragma unroll
        for (int r = 0; r < 8; ++r) {
            float4 xv = *reinterpret_cast<const float4*>(&xs[rg * 8 + r][k4 * 4]);
            acc[r] = fmaf(xv.x, w0, fmaf(xv.y, w1, fmaf(xv.z, w2, fmaf(xv.w, w3, acc[r]))));
        }
    }

    float a_l = al[j], a_r = ar[j];
    #pragma unroll
    for (int r = 0; r < 8; ++r) {
        int row = r0 + rg * 8 + r;
        if (row < NN) z[(size_t)row * F1 + j] = acc[r];
        float pl = acc[r] * a_l, pr = acc[r] * a_r;
        #pragma unroll
        for (int mm = 1; mm < 64; mm <<= 1) {
            pl += __shfl_xor(pl, mm);
            pr += __shfl_xor(pr, mm);
        }
        if (j == 0 && row < NN) { el[row] = pl; er[row] = pr; }
    }
}

// ---- GEMM2: z = h@W (NN x 64 @ 64 x 32), register-blocked.
// Block tile: 64 rows x 32 cols. Thread (j = tid&31, rg = tid>>5) computes
// 8 rows for col j. Half-wave-uniform xs reads (2 addrs/wave = free).
__global__ __launch_bounds__(256) void gemm2_kernel(
    const float* __restrict__ h, const float* __restrict__ W,
    const float* __restrict__ al, const float* __restrict__ ar,
    float* __restrict__ z, float* __restrict__ el, float* __restrict__ er)
{
    __shared__ float Ws[F1 * F2];     // 8 KB
    __shared__ float xs[64][F1];      // 16 KB
    int tid = threadIdx.x;
    int r0 = blockIdx.x * 64;

    {
        const float4* W4 = reinterpret_cast<const float4*>(W);
        float4* Ws4 = reinterpret_cast<float4*>(Ws);
        #pragma unroll
        for (int i = 0; i < 2; ++i) Ws4[tid + i * 256] = W4[tid + i * 256];
    }
    {
        float4 zero = {0.f, 0.f, 0.f, 0.f};
        #pragma unroll
        for (int i = 0; i < 4; ++i) {
            int s = tid + i * 256;
            int row = s >> 4, c4 = s & 15;
            int grow = r0 + row;
            float4 v = (grow < NN)
                ? reinterpret_cast<const float4*>(h)[(size_t)grow * 16 + c4] : zero;
            *reinterpret_cast<float4*>(&xs[row][c4 * 4]) = v;
        }
    }
    __syncthreads();

    int j = tid & 31, rg = tid >> 5;
    float acc[8] = {0.f, 0.f, 0.f, 0.f, 0.f, 0.f, 0.f, 0.f};
    for (int k4 = 0; k4 < F1 / 4; ++k4) {
        float w0 = Ws[(k4 * 4 + 0) * F2 + j];
        float w1 = Ws[(k4 * 4 + 1) * F2 + j];
        float w2 = Ws[(k4 * 4 + 2) * F2 + j];
        float w3 = Ws[(k4 * 4 + 3) * F2 + j];
        #pragma unroll
        for (int r = 0; r < 8; ++r) {
            float4 xv = *reinterpret_cast<const float4*>(&xs[rg * 8 + r][k4 * 4]);
            acc[r] = fmaf(xv.x, w0, fmaf(xv.y, w1, fmaf(xv.z, w2, fmaf(xv.w, w3, acc[r]))));
        }
    }

    float a_l = al[j], a_r = ar[j];
    #pragma unroll
    for (int r = 0; r < 8; ++r) {
        int row = r0 + rg * 8 + r;
        if (row < NN) z[(size_t)row * F2 + j] = acc[r];
        float pl = acc[r] * a_l, pr = acc[r] * a_r;
        #pragma unroll
        for (int mm = 1; mm < 32; mm <<= 1) {
            pl += __shfl_xor(pl, mm);
            pr += __shfl_xor(pr, mm);
        }
        if (j == 0 && row < NN) { el[row] = pl; er[row] = pr; }
    }
}

// ========== CSR build via 2-level counting sort (dense writes only) ==========

__global__ __launch_bounds__(256) void p1_hist_kernel(
    const int* __restrict__ dst, int* __restrict__ hist)
{
    __shared__ int h[NBK];
    int c = blockIdx.x;
    if (threadIdx.x < NBK) h[threadIdx.x] = 0;
    __syncthreads();
    int e0 = c * CHUNK;
    int e1 = (e0 + CHUNK < NE) ? e0 + CHUNK : NE;
    for (int e = e0 + threadIdx.x; e < e1; e += 256)
        atomicAdd(&h[dst[e] >> 8], 1);
    __syncthreads();
    if (threadIdx.x < NBK) hist[threadIdx.x * NC + c] = h[threadIdx.x];
}

__global__ __launch_bounds__(256) void p2a_scan_kernel(
    int* __restrict__ hist, int* __restrict__ btot)
{
    __shared__ int t[256];
    int b = blockIdx.x;
    int v = (threadIdx.x < NC) ? hist[b * NC + threadIdx.x] : 0;
    t[threadIdx.x] = v;
    __syncthreads();
    for (int off = 1; off < 256; off <<= 1) {
        int u = (threadIdx.x >= off) ? t[threadIdx.x - off] : 0;
        __syncthreads();
        t[threadIdx.x] += u;
        __syncthreads();
    }
    if (threadIdx.x < NC) hist[b * NC + threadIdx.x] = t[threadIdx.x] - v; // exclusive
    if (threadIdx.x == 255) btot[b] = t[255];
}

__global__ __launch_bounds__(256) void p2b_scan_kernel(
    const int* __restrict__ btot, int* __restrict__ bstart, int* __restrict__ row_start)
{
    __shared__ int t[256];
    int v = (threadIdx.x < NBK) ? btot[threadIdx.x] : 0;
    t[threadIdx.x] = v;
    __syncthreads();
    for (int off = 1; off < 256; off <<= 1) {
        int u = (threadIdx.x >= off) ? t[threadIdx.x - off] : 0;
        __syncthreads();
        t[threadIdx.x] += u;
        __syncthreads();
    }
    if (threadIdx.x < NBK) bstart[threadIdx.x] = t[threadIdx.x] - v;
    if (threadIdx.x == NBK) bstart[NBK] = NE;
    if (threadIdx.x == 0) row_start[NN] = NE;
}

__global__ __launch_bounds__(256) void p3_part_kernel(
    const int* __restrict__ src, const int* __restrict__ dst,
    const int* __restrict__ hist, const int* __restrict__ bstart,
    int2* __restrict__ part)
{
    __shared__ int base[NBK];
    __shared__ int cnt[NBK];
    int c = blockIdx.x;
    if (threadIdx.x < NBK) {
        base[threadIdx.x] = hist[threadIdx.x * NC + c] + bstart[threadIdx.x];
        cnt[threadIdx.x] = 0;
    }
    __syncthreads();
    int e0 = c * CHUNK;
    int e1 = (e0 + CHUNK < NE) ? e0 + CHUNK : NE;
    for (int e = e0 + threadIdx.x; e < e1; e += 256) {
        int s = src[e], d = dst[e];
        int b = d >> 8;
        int r = atomicAdd(&cnt[b], 1);
        part[base[b] + r] = make_int2(s, d);
    }
}

__global__ __launch_bounds__(256) void p4_fill_kernel(
    const int2* __restrict__ part, const int* __restrict__ bstart,
    int* __restrict__ row_start, int* __restrict__ srcs)
{
    __shared__ int deg[NPB];
    __shared__ int off[NPB];
    __shared__ int cnt[NPB];
    int b = blockIdx.x;
    int lo = bstart[b], hi = bstart[b + 1];
    deg[threadIdx.x] = 0;
    cnt[threadIdx.x] = 0;
    __syncthreads();
    for (int i = lo + threadIdx.x; i < hi; i += 256)
        atomicAdd(&deg[part[i].y & (NPB - 1)], 1);
    __syncthreads();
    int v = deg[threadIdx.x];
    off[threadIdx.x] = v;
    __syncthreads();
    for (int o = 1; o < 256; o <<= 1) {
        int u = (threadIdx.x >= o) ? off[threadIdx.x - o] : 0;
        __syncthreads();
        off[threadIdx.x] += u;
        __syncthreads();
    }
    int ex = off[threadIdx.x] - v;
    __syncthreads();
    off[threadIdx.x] = ex;
    __syncthreads();
    int node = b * NPB + threadIdx.x;
    if (node < NN) row_start[node] = lo + ex;
    for (int i = lo + threadIdx.x; i < hi; i += 256) {
        int2 e = part[i];
        int n = e.y & (NPB - 1);
        int r = atomicAdd(&cnt[n], 1);
        srcs[lo + off[n] + r] = e.x;
    }
}

// ==================== fused attention aggregation (gather, no atomics) =====
__global__ __launch_bounds__(256) void gat_agg64_kernel(
    const int* __restrict__ row_start, const int* __restrict__ srcs,
    const float* __restrict__ el, const float* __restrict__ er,
    const float* __restrict__ z, const float* __restrict__ b,
    float* __restrict__ out, float slope_out)
{
    int node = (blockIdx.x * 256 + threadIdx.x) >> 6;
    if (node >= NN) return;
    int lane = threadIdx.x & 63;
    int g = lane >> 4, c = lane & 15;
    int beg = row_start[node], end = row_start[node + 1];
    float erd = er[node];

    int i0 = beg + lane;
    float v0 = -INFINITY;
    if (i0 < end) v0 = lrelu(el[srcs[i0]] + erd, 0.2f);
    float lm = v0;
    for (int i = i0 + 64; i < end; i += 64)
        lm = fmaxf(lm, lrelu(el[srcs[i]] + erd, 0.2f));
    #pragma unroll
    for (int mm = 1; mm < 64; mm <<= 1) lm = fmaxf(lm, __shfl_xor(lm, mm));

    float preg = 0.f, ls = 0.f;
    if (i0 < end) { preg = __expf(v0 - lm); ls = preg; }
    for (int i = i0 + 64; i < end; i += 64)
        ls += __expf(lrelu(el[srcs[i]] + erd, 0.2f) - lm);
    #pragma unroll
    for (int mm = 1; mm < 64; mm <<= 1) ls += __shfl_xor(ls, mm);
    float inv_s = (ls > 0.f) ? 1.0f / ls : 0.f;

    const float4* z4 = reinterpret_cast<const float4*>(z);
    float4 acc = {0.f, 0.f, 0.f, 0.f};
    for (int ib = beg; ib < end; ib += 4) {
        int i = ib + g;
        int j = i - beg;
        float pv = __shfl(preg, j & 63);
        if (i < end) {
            int sn = srcs[i];
            if (j >= 64) pv = __expf(lrelu(el[sn] + erd, 0.2f) - lm); // rare tail
            float alpha = pv * inv_s;
            float4 zv = z4[(size_t)sn * 16 + c];
            acc.x = fmaf(alpha, zv.x, acc.x);
            acc.y = fmaf(alpha, zv.y, acc.y);
            acc.z = fmaf(alpha, zv.z, acc.z);
            acc.w = fmaf(alpha, zv.w, acc.w);
        }
    }
    #pragma unroll
    for (int mm = 16; mm < 64; mm <<= 1) {
        acc.x += __shfl_xor(acc.x, mm);
        acc.y += __shfl_xor(acc.y, mm);
        acc.z += __shfl_xor(acc.z, mm);
        acc.w += __shfl_xor(acc.w, mm);
    }
    if (g == 0) {
        float4 bb = reinterpret_cast<const float4*>(b)[c];
        float4 o;
        o.x = lrelu(acc.x + bb.x, slope_out);
        o.y = lrelu(acc.y + bb.y, slope_out);
        o.z = lrelu(acc.z + bb.z, slope_out);
        o.w = lrelu(acc.w + bb.w, slope_out);
        reinterpret_cast<float4*>(out)[(size_t)node * 16 + c] = o;
    }
}

__global__ __launch_bounds__(256) void gat_agg32_kernel(
    const int* __restrict__ row_start, const int* __restrict__ srcs,
    const float* __restrict__ el, const float* __restrict__ er,
    const float* __restrict__ z, const float* __restrict__ b,
    float* __restrict__ out, float slope_out)
{
    int node = (blockIdx.x * 256 + threadIdx.x) >> 5;
    if (node >= NN) return;
    int sub = threadIdx.x & 31;
    int base = threadIdx.x & 32;
    int g = sub >> 3, c = sub & 7;
    int beg = row_start[node], end = row_start[node + 1];
    float erd = er[node];

    int i0 = beg + sub;
    float v0 = -INFINITY;
    if (i0 < end) v0 = lrelu(el[srcs[i0]] + erd, 0.2f);
    float lm = v0;
    for (int i = i0 + 32; i < end; i += 32)
        lm = fmaxf(lm, lrelu(el[srcs[i]] + erd, 0.2f));
    #pragma unroll
    for (int mm = 1; mm < 32; mm <<= 1) lm = fmaxf(lm, __shfl_xor(lm, mm));

    float preg = 0.f, ls = 0.f;
    if (i0 < end) { preg = __expf(v0 - lm); ls = preg; }
    for (int i = i0 + 32; i < end; i += 32)
        ls += __expf(lrelu(el[srcs[i]] + erd, 0.2f) - lm);
    #pragma unroll
    for (int mm = 1; mm < 32; mm <<= 1) ls += __shfl_xor(ls, mm);
    float inv_s = (ls > 0.f) ? 1.0f / ls : 0.f;

    const float4* z4 = reinterpret_cast<const float4*>(z);
    float4 acc = {0.f, 0.f, 0.f, 0.f};
    for (int ib = beg; ib < end; ib += 4) {
        int i = ib + g;
        int j = i - beg;
        float pv = __shfl(preg, base | (j & 31));
        if (i < end) {
            int sn = srcs[i];
            if (j >= 32) pv = __expf(lrelu(el[sn] + erd, 0.2f) - lm); // rare tail
            float alpha = pv * inv_s;
            float4 zv = z4[(size_t)sn * 8 + c];
            acc.x = fmaf(alpha, zv.x, acc.x);
            acc.y = fmaf(alpha, zv.y, acc.y);
            acc.z = fmaf(alpha, zv.z, acc.z);
            acc.w = fmaf(alpha, zv.w, acc.w);
        }
    }
    #pragma unroll
    for (int mm = 8; mm < 32; mm <<= 1) {
        acc.x += __shfl_xor(acc.x, mm);
        acc.y += __shfl_xor(acc.y, mm);
        acc.z += __shfl_xor(acc.z, mm);
        acc.w += __shfl_xor(acc.w, mm);
    }
    if (g == 0) {
        float4 bb = reinterpret_cast<const float4*>(b)[c];
        float4 o;
        o.x = lrelu(acc.x + bb.x, slope_out);
        o.y = lrelu(acc.y + bb.y, slope_out);
        o.z = lrelu(acc.z + bb.z, slope_out);
        o.w = lrelu(acc.w + bb.w, slope_out);
        reinterpret_cast<float4*>(out)[(size_t)node * 8 + c] = o;
    }
}

// ---- per-graph mean pool (graph_id sorted); one block per graph
__global__ __launch_bounds__(256) void pool_kernel(
    const float* __restrict__ h2, const int* __restrict__ gid, float* __restrict__ out)
{
    int g = blockIdx.x;
    int lo = 0, hi = NN;
    while (lo < hi) { int mid = (lo + hi) >> 1; if (gid[mid] < g) lo = mid + 1; else hi = mid; }
    int start = lo;
    hi = NN;
    while (lo < hi) { int mid = (lo + hi) >> 1; if (gid[mid] < g + 1) lo = mid + 1; else hi = mid; }
    int end = lo;

    int f = threadIdx.x & 31, r = threadIdx.x >> 5;
    float acc = 0.f;
    for (int n = start + r; n < end; n += 8) acc += h2[(size_t)n * F2 + f];
    __shared__ float red[256];
    red[threadIdx.x] = acc;
    __syncthreads();
    for (int st = 128; st >= 32; st >>= 1) {
        if (threadIdx.x < st) red[threadIdx.x] += red[threadIdx.x + st];
        __syncthreads();
    }
    if (threadIdx.x < 32) {
        float cnt = (float)(end - start);
        out[g * F2 + threadIdx.x] = red[threadIdx.x] / fmaxf(cnt, 1.0f);
    }
}

extern "C" void kernel_launch(void* const* d_in, const int* in_sizes, int n_in,
                              void* d_out, int out_size, void* d_ws, size_t ws_size,
                              hipStream_t stream)
{
    const float* x   = (const float*)d_in[0];
    const int*   src = (const int*)d_in[1];
    const int*   dst = (const int*)d_in[2];
    const int*   gid = (const int*)d_in[3];
    const float* W1  = (const float*)d_in[4];
    const float* al1 = (const float*)d_in[5];
    const float* ar1 = (const float*)d_in[6];
    const float* b1  = (const float*)d_in[7];
    const float* W2  = (const float*)d_in[8];
    const float* al2 = (const float*)d_in[9];
    const float* ar2 = (const float*)d_in[10];
    const float* b2  = (const float*)d_in[11];
    float* out = (float*)d_out;

    float* ws   = (float*)d_ws;
    float* z1   = ws;                            // NN*64 floats
    float* h1   = z1 + (size_t)NN * F1;          // NN*64
    float* z2   = h1 + (size_t)NN * F1;          // NN*32
    float* h2   = z2 + (size_t)NN * F2;          // NN*32
    float* el   = h2 + (size_t)NN * F2;          // NN
    float* er   = el + NN;                       // NN
    int* row_start = (int*)(er + NN);            // NN+1
    int* srcs      = row_start + NN + 1;         // NE
    int* hist      = srcs + NE;                  // NBK*NC
    int* btot      = hist + NBK * NC;            // NBK
    int* bstart    = btot + NBK;                 // NBK+1
    // part[] aliases z1 (dead until gemm1 writes z1, which runs after p4)
    int2* part = reinterpret_cast<int2*>(z1);    // NE int2 = 6.4MB <= 12.8MB

    // ---- CSR build (counting sort; all global writes dense)
    p1_hist_kernel<<<NC, 256, 0, stream>>>(dst, hist);
    p2a_scan_kernel<<<NBK, 256, 0, stream>>>(hist, btot);
    p2b_scan_kernel<<<1, 256, 0, stream>>>(btot, bstart, row_start);
    p3_part_kernel<<<NC, 256, 0, stream>>>(src, dst, hist, bstart, part);
    p4_fill_kernel<<<NBK, 256, 0, stream>>>(part, bstart, row_start, srcs);

    // ---- layer 1
    gemm1_kernel<<<(NN + 31) / 32, 256, 0, stream>>>(x, W1, al1, ar1, z1, el, er);
    gat_agg64_kernel<<<(NN * 64 + 255) / 256, 256, 0, stream>>>(
        row_start, srcs, el, er, z1, b1, h1, 0.01f);

    // ---- layer 2
    gemm2_kernel<<<(NN + 63) / 64, 256, 0, stream>>>(h1, W2, al2, ar2, z2, el, er);
    gat_agg32_kernel<<<(NN * 32 + 255) / 256, 256, 0, stream>>>(
        row_start, srcs, el, er, z2, b2, h2, 0.01f);

    // ---- per-graph mean pool
    pool_kernel<<<NG, 256, 0, stream>>>(h2, gid, out);
}